// Round 8
// baseline (262.232 us; speedup 1.0000x reference)
//
#include <hip/hip_runtime.h>

#define CN 256
#define HN 64
#define WN 64
#define NNW 32
#define HW (HN*WN)            // 4096
#define NREF (NNW*HW)         // 131072
#define KD 256

#define BM2 128               // block M-tile
#define BN2 128               // block N-tile
#define NCH 16                // n-chunks -> grid 512 = 2 blocks/CU, one round
#define NTILES (NREF/NCH/BN2) // 64 B-tiles per block

using bf16x8 = __attribute__((ext_vector_type(8))) short;
using f32x16 = __attribute__((ext_vector_type(16))) float;

__device__ inline unsigned short f2bf(float x) {
  unsigned int u = __float_as_uint(x);
  return (unsigned short)((u + 0x7fffu + ((u >> 16) & 1u)) >> 16);
}

__device__ inline void atomicMaxFloat(float* addr, float val) {
  if (val >= 0.f) atomicMax(reinterpret_cast<int*>(addr), __float_as_int(val));
  else            atomicMin(reinterpret_cast<unsigned int*>(addr), __float_as_uint(val));
}

__device__ inline void gload_lds16(const void* g, void* l) {
  __builtin_amdgcn_global_load_lds(
      (const __attribute__((address_space(1))) void*)g,
      (__attribute__((address_space(3))) void*)l, 16, 0, 0);
}

// ---------------- normalize (refs blocks 0..2047, img blocks 2048..2111) ----
__global__ __launch_bounds__(256)
void norm_kernel(const float* __restrict__ refs, const float* __restrict__ img,
                 unsigned short* __restrict__ Rb, unsigned short* __restrict__ Qb,
                 float* __restrict__ out) {
  __shared__ float tile[CN][WN + 1];
  __shared__ float ssq[4][WN];
  __shared__ float scl[WN];
  const int bid = blockIdx.x;
  const int t = threadIdx.x;
  const float* src; unsigned short* dst; int nh;
  if (bid < NNW * HN) { src = refs; dst = Rb; nh = bid; }
  else {
    src = img; dst = Qb; nh = bid - NNW * HN;
    if (t < 64) out[(size_t)nh * 64 + t] = -INFINITY;   // init output
  }
  const float* base = src + (size_t)(nh >> 6) * (CN * (size_t)HW) + (size_t)(nh & 63) * WN;

  const int c16 = t >> 4, w4 = (t & 15) * 4;
#pragma unroll
  for (int j = 0; j < 16; ++j) {
    int c = j * 16 + c16;
    float4 v = *(const float4*)&base[(size_t)c * HW + w4];
    tile[c][w4 + 0] = v.x; tile[c][w4 + 1] = v.y;
    tile[c][w4 + 2] = v.z; tile[c][w4 + 3] = v.w;
  }
  __syncthreads();
  {
    int w = t & 63, vv = t >> 6;
    float s = 0.f;
#pragma unroll 8
    for (int cc = 0; cc < 64; ++cc) { float x = tile[vv * 64 + cc][w]; s += x * x; }
    ssq[vv][w] = s;
  }
  __syncthreads();
  if (t < 64)
    scl[t] = 1.f / fmaxf(sqrtf(ssq[0][t] + ssq[1][t] + ssq[2][t] + ssq[3][t]), 1e-12f);
  __syncthreads();
  const int w = t >> 2, cq = t & 3;
  unsigned short* orow = dst + ((size_t)nh * WN + w) * KD;
  const float sc = scl[w];
#pragma unroll
  for (int j = 0; j < 8; ++j) {
    int c0 = (j * 4 + cq) * 8;
    bf16x8 o;
#pragma unroll
    for (int k = 0; k < 8; ++k) o[k] = (short)f2bf(tile[c0 + k][w] * sc);
    *(bf16x8*)&orow[c0] = o;
  }
}

// ---- GEMM-max: A resident in regs (32x32x16 MFMA), B via 4-sub LDS ring ----
#define BARR() __builtin_amdgcn_s_barrier()
#define SCHED0() __builtin_amdgcn_sched_barrier(0)
#define GATE(N) asm volatile("s_waitcnt vmcnt(" #N ")" ::: "memory")
#define LGKM0() asm volatile("s_waitcnt lgkmcnt(0)" ::: "memory")

// stage one 16KB sub (128 rows x 64 k): 4 gloads/thread, wave w rows [w*32, w*32+32)
#define STG4(SUB, PTR, KOFF) do { \
  _Pragma("unroll") \
  for (int p = 0; p < 4; ++p) \
    gload_lds16((PTR) + (KOFF) + p * 8 * KD, &lds[SUB][(w * 32 + p * 8) * 64]); \
} while (0)

// one phase: consume k-half PAIR (128 k, subs PAIR*2, PAIR*2+1); stage per STGM
// STGM: 1 = stage pair1 (this tile k128..255); 2 = stage pair0 (next tile k0..127); 0 = none
#define PH2(PAIR, ACM, STGM, GN) do { \
  if ((STGM) == 1) { STG4(2, rs, 128); STG4(3, rs, 192); } \
  if ((STGM) == 2) { STG4(0, rs + 32768, 0); STG4(1, rs + 32768, 64); } \
  GATE(GN); BARR(); SCHED0(); \
  __builtin_amdgcn_s_setprio(1); \
  _Pragma("unroll") \
  for (int kf = 0; kf < 8; ++kf) { \
    const int sub = (PAIR) * 2 + (kf >> 2); \
    const int ck = ((((kf & 3) * 2 + hi) ^ l7)) * 8; \
    bf16x8 b0 = *(const bf16x8*)&lds[sub][nrowb * 64 + ck]; \
    bf16x8 b1 = *(const bf16x8*)&lds[sub][(nrowb + 32) * 64 + ck]; \
    _Pragma("unroll") \
    for (int mi = 0; mi < 2; ++mi) { \
      acc[mi][0] = __builtin_amdgcn_mfma_f32_32x32x16_bf16(a[mi][(PAIR)*8 + kf], b0, ((ACM) || kf) ? acc[mi][0] : ZZ, 0, 0, 0); \
      acc[mi][1] = __builtin_amdgcn_mfma_f32_32x32x16_bf16(a[mi][(PAIR)*8 + kf], b1, ((ACM) || kf) ? acc[mi][1] : ZZ, 0, 0, 0); \
    } \
  } \
  __builtin_amdgcn_s_setprio(0); \
  SCHED0(); BARR(); \
} while (0)

#define FOLD() do { \
  _Pragma("unroll") \
  for (int mi = 0; mi < 2; ++mi) \
  _Pragma("unroll") \
  for (int e = 0; e < 16; ++e) \
    run[mi][e] = fmaxf(run[mi][e], fmaxf(acc[mi][0][e], acc[mi][1][e])); \
} while (0)

__global__ __launch_bounds__(256, 2)
void simmax_kernel(const unsigned short* __restrict__ Q,
                   const unsigned short* __restrict__ R,
                   float* __restrict__ out) {
  // 4 ring subs: [128 rows][64 k] bf16, XOR-chunk swizzled. 64 KB total.
  __shared__ unsigned short lds[4][8192];

  const int t = threadIdx.x;
  const int lane = t & 63;
  const int w  = t >> 6;        // 0..3
  const int wm = w >> 1;        // 0..1
  const int wn = w & 1;         // 0..1
  const int hi = lane >> 5;     // 0..1
  const int l7 = lane & 7;

  // bijective XCD swizzle: XCD x hosts wg [x*64, x*64+64) = 2 nch x 32 bm
  const int wg  = (blockIdx.x & 7) * 64 + (blockIdx.x >> 3);
  const int nch = wg >> 5;      // 0..15
  const int bm  = wg & 31;      // 0..31

  // staging: row-in-8 = lane>>3, phys chunk lane&7, source chunk = (lane&7)^(lane>>3)
  const int srow = lane >> 3;
  const int schunk = (lane & 7) ^ srow;
  const unsigned short* qsrcA = Q + (size_t)(bm * BM2 + w * 32 + srow) * KD + schunk * 8;
  const unsigned short* rsrc0 = R + (size_t)((size_t)nch * (NTILES * BN2) + w * 32 + srow) * KD + schunk * 8;

  // MFMA read rows (row&7 == lane&7 for all, so phys chunk = logical ^ l7)
  const int mrowb = wm * 64 + (lane & 31);   // + mi*32
  const int nrowb = wn * 64 + (lane & 31);   // + ni*32

  const f32x16 ZZ = {0,0,0,0,0,0,0,0,0,0,0,0,0,0,0,0};
  f32x16 acc[2][2];
  f32x16 run[2];
#pragma unroll
  for (int mi = 0; mi < 2; ++mi)
#pragma unroll
    for (int e = 0; e < 16; ++e) run[mi][e] = -1e30f;

  // ---- prologue: stage A (128 x 256) through the 4 subs, read to registers
#pragma unroll
  for (int s = 0; s < 4; ++s)
    STG4(s, qsrcA, s * 64);
  GATE(0); BARR(); SCHED0();

  bf16x8 a[2][16];              // resident A: 2 m-frags x 16 k-frags (k=16 each)
#pragma unroll
  for (int mi = 0; mi < 2; ++mi) {
    const int rb = (mrowb + mi * 32) * 64;
#pragma unroll
    for (int kf = 0; kf < 16; ++kf)
      a[mi][kf] = *(const bf16x8*)&lds[kf >> 2][rb + ((((kf & 3) * 2 + hi) ^ l7)) * 8];
  }
  LGKM0(); BARR();              // all waves done reading A before B overwrites

  // ---- B ring: phase q stages the pair consumed at q+1; GATE(8) = 1 phase deep
  const unsigned short* rs = rsrc0;
  STG4(0, rs, 0); STG4(1, rs, 64);   // data for q=0

  for (int bt = 0; bt < NTILES - 1; ++bt) {
    PH2(0, 0, 1, 8);     // consume k0..127, stage pair1 <- this tile k128..255
    PH2(1, 1, 2, 8);     // consume k128..255, stage pair0 <- next tile k0..127
    FOLD();
    rs += 32768;
  }
  PH2(0, 0, 1, 8);       // last tile first half
  PH2(1, 1, 0, 0);       // last half, drain
  FOLD();

  // reduce over the 32 column-lanes, one atomic per output row
#pragma unroll
  for (int mi = 0; mi < 2; ++mi)
#pragma unroll
  for (int e = 0; e < 16; ++e) {
    float v = run[mi][e];
    v = fmaxf(v, __shfl_xor(v, 1));
    v = fmaxf(v, __shfl_xor(v, 2));
    v = fmaxf(v, __shfl_xor(v, 4));
    v = fmaxf(v, __shfl_xor(v, 8));
    v = fmaxf(v, __shfl_xor(v, 16));
    if ((lane & 31) == 0) {
      // C/D layout 32x32: row = (e&3) + 8*(e>>2) + 4*hi
      int row = bm * BM2 + wm * 64 + mi * 32 + (e & 3) + 8 * (e >> 2) + 4 * hi;
      atomicMaxFloat(&out[row], v);
    }
  }
}

extern "C" void kernel_launch(void* const* d_in, const int* in_sizes, int n_in,
                              void* d_out, int out_size, void* d_ws, size_t ws_size,
                              hipStream_t stream) {
  const float* refs = (const float*)d_in[0];
  const float* img  = (const float*)d_in[1];
  float* out = (float*)d_out;

  unsigned short* Rb = (unsigned short*)d_ws;                 // 131072*256 bf16 = 64MB
  unsigned short* Qb = Rb + (size_t)NREF * KD;                // 4096*256 bf16 = 2MB

  hipLaunchKernelGGL(norm_kernel, dim3(NNW * HN + HN), dim3(256), 0, stream,
                     refs, img, Rb, Qb, out);
  hipLaunchKernelGGL(simmax_kernel, dim3(NCH * (HW / BM2)), dim3(256), 0, stream,
                     Qb, Rb, out);
}

// Round 9
// 254.241 us; speedup vs baseline: 1.0314x; 1.0314x over previous
//
#include <hip/hip_runtime.h>

#define CN 256
#define HN 64
#define WN 64
#define NNW 32
#define HW (HN*WN)            // 4096
#define NREF (NNW*HW)         // 131072
#define KD 256

#define BM2 128               // block M-tile
#define BN2 128               // block N-tile
#define NCH 16                // n-chunks -> grid 512 = 2 blocks/CU, one round
#define NTILES (NREF/NCH/BN2) // 64 B-tiles per block

using bf16x8 = __attribute__((ext_vector_type(8))) short;
using f32x4  = __attribute__((ext_vector_type(4))) float;

__device__ inline unsigned short f2bf(float x) {
  unsigned int u = __float_as_uint(x);
  return (unsigned short)((u + 0x7fffu + ((u >> 16) & 1u)) >> 16);
}

__device__ inline void atomicMaxFloat(float* addr, float val) {
  if (val >= 0.f) atomicMax(reinterpret_cast<int*>(addr), __float_as_int(val));
  else            atomicMin(reinterpret_cast<unsigned int*>(addr), __float_as_uint(val));
}

__device__ inline void gload_lds16(const void* g, void* l) {
  __builtin_amdgcn_global_load_lds(
      (const __attribute__((address_space(1))) void*)g,
      (__attribute__((address_space(3))) void*)l, 16, 0, 0);
}

// ---------------- normalize (refs blocks 0..2047, img blocks 2048..2111) ----
__global__ __launch_bounds__(256)
void norm_kernel(const float* __restrict__ refs, const float* __restrict__ img,
                 unsigned short* __restrict__ Rb, unsigned short* __restrict__ Qb,
                 float* __restrict__ out) {
  __shared__ float tile[CN][WN + 1];
  __shared__ float ssq[4][WN];
  __shared__ float scl[WN];
  const int bid = blockIdx.x;
  const int t = threadIdx.x;
  const float* src; unsigned short* dst; int nh;
  if (bid < NNW * HN) { src = refs; dst = Rb; nh = bid; }
  else {
    src = img; dst = Qb; nh = bid - NNW * HN;
    if (t < 64) out[(size_t)nh * 64 + t] = -INFINITY;   // init output
  }
  const float* base = src + (size_t)(nh >> 6) * (CN * (size_t)HW) + (size_t)(nh & 63) * WN;

  const int c16 = t >> 4, w4 = (t & 15) * 4;
#pragma unroll
  for (int j = 0; j < 16; ++j) {
    int c = j * 16 + c16;
    float4 v = *(const float4*)&base[(size_t)c * HW + w4];
    tile[c][w4 + 0] = v.x; tile[c][w4 + 1] = v.y;
    tile[c][w4 + 2] = v.z; tile[c][w4 + 3] = v.w;
  }
  __syncthreads();
  {
    int w = t & 63, vv = t >> 6;
    float s = 0.f;
#pragma unroll 8
    for (int cc = 0; cc < 64; ++cc) { float x = tile[vv * 64 + cc][w]; s += x * x; }
    ssq[vv][w] = s;
  }
  __syncthreads();
  if (t < 64)
    scl[t] = 1.f / fmaxf(sqrtf(ssq[0][t] + ssq[1][t] + ssq[2][t] + ssq[3][t]), 1e-12f);
  __syncthreads();
  const int w = t >> 2, cq = t & 3;
  unsigned short* orow = dst + ((size_t)nh * WN + w) * KD;
  const float sc = scl[w];
#pragma unroll
  for (int j = 0; j < 8; ++j) {
    int c0 = (j * 4 + cq) * 8;
    bf16x8 o;
#pragma unroll
    for (int k = 0; k < 8; ++k) o[k] = (short)f2bf(tile[c0 + k][w] * sc);
    *(bf16x8*)&orow[c0] = o;
  }
}

// ---- GEMM-max: A resident in regs (16x16 MFMA), merged 128k phases ---------
#define BARR() __builtin_amdgcn_s_barrier()
#define SCHED0() __builtin_amdgcn_sched_barrier(0)
#define GATE(N) asm volatile("s_waitcnt vmcnt(" #N ")" ::: "memory")
#define LGKM0() asm volatile("s_waitcnt lgkmcnt(0)" ::: "memory")

// stage one 16KB sub (128 rows x 64 k): 4 gloads/thread, wave w rows [w*32, w*32+32)
#define STG4(SUB, PTR, KOFF) do { \
  _Pragma("unroll") \
  for (int p = 0; p < 4; ++p) \
    gload_lds16((PTR) + (KOFF) + p * 8 * KD, &lds[SUB][(w * 32 + p * 8) * 64]); \
} while (0)

// consume one sub (64 k): round-7 verified conflict-free read pattern
// j = position of SUB within the pair (0 or 1); ACM0 = accumulate on very first chain
#define HALF(SUB, J, ACM0) do { \
  bf16x8 bb[2][4]; \
  _Pragma("unroll") \
  for (int ks = 0; ks < 2; ++ks) \
  _Pragma("unroll") \
  for (int ni = 0; ni < 4; ++ni) \
    bb[ks][ni] = *(const bf16x8*)&lds[SUB][(nrow + ni * 16) * 64 + (ks ? (pk0 ^ 32) : pk0)]; \
  __builtin_amdgcn_s_setprio(1); \
  _Pragma("unroll") \
  for (int ks = 0; ks < 2; ++ks) \
  _Pragma("unroll") \
  for (int mi = 0; mi < 4; ++mi) \
  _Pragma("unroll") \
  for (int ni = 0; ni < 4; ++ni) \
    acc[mi][ni] = __builtin_amdgcn_mfma_f32_16x16x32_bf16(a[mi][(SUB)*2 + ks], bb[ks][ni], \
                      ((ACM0) || (J) || ks) ? acc[mi][ni] : ZZ, 0, 0, 0); \
  __builtin_amdgcn_s_setprio(0); \
} while (0)

// merged phase: consume pair PAIR (subs 2P, 2P+1 = 128 k); stage per STGM
// STGM: 1 = stage pair1 (this tile k128..255); 2 = stage pair0 (next tile); 0 = none
#define PH(PAIR, ACM0, STGM, GN) do { \
  if ((STGM) == 1) { STG4(2, rs, 128); STG4(3, rs, 192); } \
  if ((STGM) == 2) { STG4(0, rs + 32768, 0); STG4(1, rs + 32768, 64); } \
  GATE(GN); BARR(); SCHED0(); \
  HALF((PAIR)*2,     0, ACM0); \
  HALF((PAIR)*2 + 1, 1, ACM0); \
  SCHED0(); BARR(); \
} while (0)

#define FOLD() do { \
  _Pragma("unroll") \
  for (int mi = 0; mi < 4; ++mi) \
  _Pragma("unroll") \
  for (int ee = 0; ee < 4; ++ee) { \
    float v0 = fmaxf(acc[mi][0][ee], acc[mi][1][ee]); \
    float v1 = fmaxf(acc[mi][2][ee], acc[mi][3][ee]); \
    run[mi][ee] = fmaxf(run[mi][ee], fmaxf(v0, v1)); \
  } \
} while (0)

__global__ __launch_bounds__(256, 2)
void simmax_kernel(const unsigned short* __restrict__ Q,
                   const unsigned short* __restrict__ R,
                   float* __restrict__ out) {
  // 4 ring subs: [128 rows][64 k] bf16, XOR-chunk swizzled. 64 KB total.
  __shared__ unsigned short lds[4][8192];

  const int t = threadIdx.x;
  const int lane = t & 63;
  const int w  = t >> 6;        // 0..3
  const int wm = w >> 1;        // 0..1
  const int wn = w & 1;         // 0..1

  // bijective XCD swizzle: XCD x hosts wg [x*64, x*64+64) = 2 nch x 32 bm
  const int wg  = (blockIdx.x & 7) * 64 + (blockIdx.x >> 3);
  const int nch = wg >> 5;      // 0..15
  const int bm  = wg & 31;      // 0..31

  // staging: row-in-8 = lane>>3, phys chunk lane&7, source chunk = (lane&7)^(lane>>3)
  const int srow = lane >> 3;
  const int schunk = (lane & 7) ^ srow;
  const unsigned short* qsrcA = Q + (size_t)(bm * BM2 + w * 32 + srow) * KD + schunk * 8;
  const unsigned short* rsrc0 = R + (size_t)((size_t)nch * (NTILES * BN2) + w * 32 + srow) * KD + schunk * 8;

  // read geometry (round-7 verified): phys chunk = (ks*4 + (lane>>4)) ^ (lane&7)
  const int pk0 = (((lane >> 4) ^ (lane & 7))) * 8;   // ks=0 chunk (shorts)
  const int mrow = wm * 64 + (lane & 15);
  const int nrow = wn * 64 + (lane & 15);

  const f32x4 ZZ = {0.f, 0.f, 0.f, 0.f};
  f32x4 acc[4][4];
  f32x4 run[4];
#pragma unroll
  for (int mi = 0; mi < 4; ++mi)
#pragma unroll
    for (int ee = 0; ee < 4; ++ee) run[mi][ee] = -1e30f;

  // ---- prologue: stage A (128 x 256) through the 4 subs, read to registers
#pragma unroll
  for (int s = 0; s < 4; ++s)
    STG4(s, qsrcA, s * 64);
  GATE(0); BARR(); SCHED0();

  bf16x8 a[4][8];               // resident A: 4 m-frags x 8 k-frags = 128 VGPR
#pragma unroll
  for (int mi = 0; mi < 4; ++mi) {
    const int rb = (mrow + mi * 16) * 64;
#pragma unroll
    for (int kq = 0; kq < 4; ++kq) {
      a[mi][kq * 2 + 0] = *(const bf16x8*)&lds[kq][rb + pk0];
      a[mi][kq * 2 + 1] = *(const bf16x8*)&lds[kq][rb + (pk0 ^ 32)];
    }
  }
  LGKM0(); BARR();              // all waves done reading A before B overwrites

  // ---- B ring: 2 pairs; phase q stages the pair consumed at q+1; GATE(8)
  const unsigned short* rs = rsrc0;
  STG4(0, rs, 0); STG4(1, rs, 64);   // pair0 for first phase

  for (int bt = 0; bt < NTILES - 1; ++bt) {
    PH(0, 0, 1, 8);     // consume k0..127,  stage pair1 <- this tile k128..255
    PH(1, 1, 2, 8);     // consume k128..255, stage pair0 <- next tile k0..127
    FOLD();
    rs += 32768;
  }
  PH(0, 0, 1, 8);       // last tile first half
  PH(1, 1, 0, 0);       // last half, drain
  FOLD();

  // reduce over the 16 column-lanes, one atomic per output row
#pragma unroll
  for (int mi = 0; mi < 4; ++mi)
#pragma unroll
  for (int ee = 0; ee < 4; ++ee) {
    float v = run[mi][ee];
    v = fmaxf(v, __shfl_xor(v, 1));
    v = fmaxf(v, __shfl_xor(v, 2));
    v = fmaxf(v, __shfl_xor(v, 4));
    v = fmaxf(v, __shfl_xor(v, 8));
    if ((lane & 15) == 0)
      atomicMaxFloat(&out[bm * BM2 + wm * 64 + mi * 16 + (lane >> 4) * 4 + ee], v);
  }
}

extern "C" void kernel_launch(void* const* d_in, const int* in_sizes, int n_in,
                              void* d_out, int out_size, void* d_ws, size_t ws_size,
                              hipStream_t stream) {
  const float* refs = (const float*)d_in[0];
  const float* img  = (const float*)d_in[1];
  float* out = (float*)d_out;

  unsigned short* Rb = (unsigned short*)d_ws;                 // 131072*256 bf16 = 64MB
  unsigned short* Qb = Rb + (size_t)NREF * KD;                // 4096*256 bf16 = 2MB

  hipLaunchKernelGGL(norm_kernel, dim3(NNW * HN + HN), dim3(256), 0, stream,
                     refs, img, Rb, Qb, out);
  hipLaunchKernelGGL(simmax_kernel, dim3(NCH * (HW / BM2)), dim3(256), 0, stream,
                     Qb, Rb, out);
}

// Round 10
// 222.643 us; speedup vs baseline: 1.1778x; 1.1419x over previous
//
#include <hip/hip_runtime.h>

#define CN 256
#define HN 64
#define WN 64
#define NNW 32
#define HW (HN*WN)            // 4096
#define NREF (NNW*HW)         // 131072
#define KD 256

#define BMT 256               // block M tile
#define BNT 128               // B rows per K-resident tile
#define NCHV 16               // n-chunks (= 4096/BMT m-tiles -> grid 256 = 1/CU)
#define NTILES (NREF/NCHV/BNT) // 64

using bf16x8 = __attribute__((ext_vector_type(8))) short;
using f32x4  = __attribute__((ext_vector_type(4))) float;

__device__ inline unsigned short f2bf(float x) {
  unsigned int u = __float_as_uint(x);
  return (unsigned short)((u + 0x7fffu + ((u >> 16) & 1u)) >> 16);
}

__device__ inline void atomicMaxFloat(float* addr, float val) {
  if (val >= 0.f) atomicMax(reinterpret_cast<int*>(addr), __float_as_int(val));
  else            atomicMin(reinterpret_cast<unsigned int*>(addr), __float_as_uint(val));
}

__device__ inline void gload_lds16(const void* g, void* l) {
  __builtin_amdgcn_global_load_lds(
      (const __attribute__((address_space(1))) void*)g,
      (__attribute__((address_space(3))) void*)l, 16, 0, 0);
}

// ---------------- normalize (refs blocks 0..2047, img blocks 2048..2111) ----
__global__ __launch_bounds__(256)
void norm_kernel(const float* __restrict__ refs, const float* __restrict__ img,
                 unsigned short* __restrict__ Rb, unsigned short* __restrict__ Qb,
                 float* __restrict__ out) {
  __shared__ float tile[CN][WN + 1];
  __shared__ float ssq[4][WN];
  __shared__ float scl[WN];
  const int bid = blockIdx.x;
  const int t = threadIdx.x;
  const float* src; unsigned short* dst; int nh;
  if (bid < NNW * HN) { src = refs; dst = Rb; nh = bid; }
  else {
    src = img; dst = Qb; nh = bid - NNW * HN;
    if (t < 64) out[(size_t)nh * 64 + t] = -INFINITY;   // init output
  }
  const float* base = src + (size_t)(nh >> 6) * (CN * (size_t)HW) + (size_t)(nh & 63) * WN;

  const int c16 = t >> 4, w4 = (t & 15) * 4;
#pragma unroll
  for (int j = 0; j < 16; ++j) {
    int c = j * 16 + c16;
    float4 v = *(const float4*)&base[(size_t)c * HW + w4];
    tile[c][w4 + 0] = v.x; tile[c][w4 + 1] = v.y;
    tile[c][w4 + 2] = v.z; tile[c][w4 + 3] = v.w;
  }
  __syncthreads();
  {
    int w = t & 63, vv = t >> 6;
    float s = 0.f;
#pragma unroll 8
    for (int cc = 0; cc < 64; ++cc) { float x = tile[vv * 64 + cc][w]; s += x * x; }
    ssq[vv][w] = s;
  }
  __syncthreads();
  if (t < 64)
    scl[t] = 1.f / fmaxf(sqrtf(ssq[0][t] + ssq[1][t] + ssq[2][t] + ssq[3][t]), 1e-12f);
  __syncthreads();
  const int w = t >> 2, cq = t & 3;
  unsigned short* orow = dst + ((size_t)nh * WN + w) * KD;
  const float sc = scl[w];
#pragma unroll
  for (int j = 0; j < 8; ++j) {
    int c0 = (j * 4 + cq) * 8;
    bf16x8 o;
#pragma unroll
    for (int k = 0; k < 8; ++k) o[k] = (short)f2bf(tile[c0 + k][w] * sc);
    *(bf16x8*)&orow[c0] = o;
  }
}

// ---- GEMM-max: A in regs, full-K B tiles double-buffered, ni-strip fold ----
#define BARR() __builtin_amdgcn_s_barrier()
#define SCHED0() __builtin_amdgcn_sched_barrier(0)
#define GATE(N) asm volatile("s_waitcnt vmcnt(" #N ")" ::: "memory")
#define LGKM0() asm volatile("s_waitcnt lgkmcnt(0)" ::: "memory")

// stage one B tile (128 rows x 256 k = 64KB) into buf P (subs P*4..P*4+3):
// wave wid covers sub wid>>1, rows (wid&1)*64..+64 -> 8 gloads/thread
#define STGB(P, TOFF) do { \
  _Pragma("unroll") \
  for (int q = 0; q < 8; ++q) \
    gload_lds16(rsb + (TOFF) + q * 8 * KD, \
                &lds[(P) * 4 + (wid >> 1)][(wid & 1) * 4096 + q * 512]); \
} while (0)

// one ni-strip: 8 B-frag reads + 32 MFMA chain (acc fresh per strip) + fold
#define STRIP(P, NI) do { \
  bf16x8 bb[8]; \
  _Pragma("unroll") \
  for (int kf = 0; kf < 8; ++kf) \
    bb[kf] = *(const bf16x8*)&lds[(P) * 4 + (kf >> 1)] \
        [(nrow + (NI) * 16) * 64 + (((kf & 1) * 4 + (lane >> 4)) ^ l7) * 8]; \
  f32x4 acc[4]; \
  __builtin_amdgcn_s_setprio(1); \
  _Pragma("unroll") \
  for (int kf = 0; kf < 8; ++kf) \
  _Pragma("unroll") \
  for (int mi = 0; mi < 4; ++mi) \
    acc[mi] = __builtin_amdgcn_mfma_f32_16x16x32_bf16(a[mi][kf], bb[kf], \
                  kf ? acc[mi] : ZZ, 0, 0, 0); \
  __builtin_amdgcn_s_setprio(0); \
  _Pragma("unroll") \
  for (int mi = 0; mi < 4; ++mi) \
  _Pragma("unroll") \
  for (int ee = 0; ee < 4; ++ee) \
    run[mi][ee] = fmaxf(run[mi][ee], acc[mi][ee]); \
} while (0)

#define STRIPS(P) do { STRIP(P, 0); STRIP(P, 1); STRIP(P, 2); STRIP(P, 3); } while (0)

__global__ __launch_bounds__(512, 2)
void simmax_kernel(const unsigned short* __restrict__ Q,
                   const unsigned short* __restrict__ R,
                   float* __restrict__ out) {
  // 8 subs of [128 rows][64 k] bf16: subs 0-3 = buf0, 4-7 = buf1. 128 KB.
  __shared__ unsigned short lds[8][8192];

  const int t = threadIdx.x;
  const int lane = t & 63;
  const int wid = t >> 6;       // 0..7
  const int wm = wid >> 1;      // 0..3 (M)
  const int wn = wid & 1;       // 0..1 (N)
  const int l7 = lane & 7;

  // bijective XCD swizzle: XCD x hosts wg [x*32, x*32+32) = 2 nch x 16 bm
  const int wg  = (blockIdx.x & 7) * 32 + (blockIdx.x >> 3);
  const int nch = wg >> 4;      // 0..15
  const int bm  = wg & 15;      // 0..15

  // staging: row-in-8 = lane>>3, phys chunk lane&7, source chunk = (lane&7)^(lane>>3)
  const int srow = lane >> 3;
  const int schunk = (lane & 7) ^ srow;
  // A source: wave wid stages sub wid: rows (wid>>2)*128.., k (wid&3)*64..
  const unsigned short* qsb = Q + (size_t)(bm * BMT + (wid >> 2) * 128 + srow) * KD
                                + (wid & 3) * 64 + schunk * 8;
  // B source: wave wid stages sub wid>>1 rows (wid&1)*64.., k (wid>>1)*64..
  const unsigned short* rsb = R + (size_t)((size_t)nch * (NTILES * BNT) + (wid & 1) * 64 + srow) * KD
                                + (wid >> 1) * 64 + schunk * 8;

  const int mrow = wm * 64 + (lane & 15);   // A row base (0..255)
  const int nrow = wn * 64 + (lane & 15);   // B row base (0..127)

  const f32x4 ZZ = {0.f, 0.f, 0.f, 0.f};
  f32x4 run[4];
#pragma unroll
  for (int mi = 0; mi < 4; ++mi)
#pragma unroll
    for (int ee = 0; ee < 4; ++ee) run[mi][ee] = -1e30f;

  // ---- prologue: stage A (256 x 256 = 128KB) across all 8 subs, read to regs
#pragma unroll
  for (int p = 0; p < 16; ++p)
    gload_lds16(qsb + p * 8 * KD, &lds[wid][p * 512]);
  GATE(0); BARR(); SCHED0();

  bf16x8 a[4][8];               // resident A: 4 m-frags x 8 k-frags
#pragma unroll
  for (int mi = 0; mi < 4; ++mi) {
    const int sub4 = ((wm * 4 + mi) >> 3) * 4;         // 0 or 4 (A row >= 128)
    const int r7 = (mrow + mi * 16) & 127;
#pragma unroll
    for (int kf = 0; kf < 8; ++kf)
      a[mi][kf] = *(const bf16x8*)&lds[sub4 + (kf >> 1)]
          [r7 * 64 + (((kf & 1) * 4 + (lane >> 4)) ^ l7) * 8];
  }
  LGKM0(); BARR();              // all waves done reading A before B overwrites

  // ---- B tiles: double-buffered full-K tiles; 1 gate + 2 barriers per tile
  STGB(0, 0);                   // tile 0 -> buf 0
  for (int bt = 0; bt < NTILES - 1; ++bt) {
    STGB((bt + 1) & 1, (bt + 1) * (BNT * KD));   // stage next tile
    GATE(8); BARR(); SCHED0();                   // this tile's stages retired
    STRIPS(bt & 1);
    BARR();                                      // reads done before next overwrite
  }
  GATE(0); BARR(); SCHED0();
  STRIPS((NTILES - 1) & 1);

  // reduce over the 16 column-lanes, one atomic per output row
#pragma unroll
  for (int mi = 0; mi < 4; ++mi)
#pragma unroll
  for (int ee = 0; ee < 4; ++ee) {
    float v = run[mi][ee];
    v = fmaxf(v, __shfl_xor(v, 1));
    v = fmaxf(v, __shfl_xor(v, 2));
    v = fmaxf(v, __shfl_xor(v, 4));
    v = fmaxf(v, __shfl_xor(v, 8));
    if ((lane & 15) == 0)
      atomicMaxFloat(&out[bm * BMT + wm * 64 + mi * 16 + (lane >> 4) * 4 + ee], v);
  }
}

extern "C" void kernel_launch(void* const* d_in, const int* in_sizes, int n_in,
                              void* d_out, int out_size, void* d_ws, size_t ws_size,
                              hipStream_t stream) {
  const float* refs = (const float*)d_in[0];
  const float* img  = (const float*)d_in[1];
  float* out = (float*)d_out;

  unsigned short* Rb = (unsigned short*)d_ws;                 // 131072*256 bf16 = 64MB
  unsigned short* Qb = Rb + (size_t)NREF * KD;                // 4096*256 bf16 = 2MB

  hipLaunchKernelGGL(norm_kernel, dim3(NNW * HN + HN), dim3(256), 0, stream,
                     refs, img, Rb, Qb, out);
  hipLaunchKernelGGL(simmax_kernel, dim3(NCHV * (HW / BMT)), dim3(512), 0, stream,
                     Qb, Rb, out);
}